// Round 2
// baseline (871.497 us; speedup 1.0000x reference)
//
#include <hip/hip_runtime.h>
#include <hip/hip_bf16.h>

// DiversityMemory: out[256,65536] = inputs[256,2048] @ features[65536,2048]^T
// R2: BM=256 x BN=64 per block, 256 threads (4 waves, 64x64 each).
//  - features (HBM-critical stream) staged 2xfloat4/thread -> bf16 -> LDS dbuf,
//    one barrier/iter, next-tile prefetch in flight across the whole compute phase
//  - inputs (2 MB, L2-resident) read directly into A fragments each iter, no LDS
//  - launch_bounds(256,3): 170-VGPR cap, no spill (R1's 512x4 => 128 cap spilled)

typedef __bf16 bf16x8 __attribute__((ext_vector_type(8)));
typedef float  f32x4  __attribute__((ext_vector_type(4)));

constexpr int K = 2048, N = 65536, M = 256;
constexpr int BN = 64, BK = 32;
constexpr int THREADS = 256;

__device__ inline uint2 cvt4(float4 v) {
    __hip_bfloat162 lo = __float22bfloat162_rn(make_float2(v.x, v.y));
    __hip_bfloat162 hi = __float22bfloat162_rn(make_float2(v.z, v.w));
    union { __hip_bfloat162 h; unsigned u; } a, b;
    a.h = lo; b.h = hi;
    return make_uint2(a.u, b.u);
}

__global__ __launch_bounds__(THREADS, 3)
void dm_gemm(const float* __restrict__ A,   // inputs   [256][2048]
             const float* __restrict__ F,   // features [65536][2048]
             float* __restrict__ C) {       // out      [256][65536]
    __shared__ __hip_bfloat16 Bs[2][BN * BK];   // 2 x 4 KB double buffer

    const int tid  = threadIdx.x;
    const int lane = tid & 63;
    const int w    = tid >> 6;       // wave 0..3 -> rows w*64..+63
    const int r15  = lane & 15;
    const int quad = lane >> 4;
    const int n0   = blockIdx.x * BN;

    // ---- B staging: thread covers (rowB = tid>>2, k = (tid&3)*8 .. +8)
    const int rowB = tid >> 2;
    const int kkB  = (tid & 3) * 8;
    const float* Fg = F + (size_t)(n0 + rowB) * K + kkB;
    __hip_bfloat16* BsW[2] = { &Bs[0][rowB * BK + kkB], &Bs[1][rowB * BK + kkB] };

    // ---- A fragment base: row = w*64 + mi*16 + r15, k = k0 + quad*8
    const float* Ab = A + (size_t)(w * 64 + r15) * K + quad * 8;

    f32x4 acc[4][4] = {};   // 64 VGPRs

    // prologue: tile 0 staged loads
    float4 b0 = *reinterpret_cast<const float4*>(Fg);
    float4 b1 = *reinterpret_cast<const float4*>(Fg + 4);

    for (int k0 = 0; k0 < K; k0 += BK) {
        const int p = (k0 >> 5) & 1;

        // ---- publish staged tile k into LDS[p] (one 16B write/thread)
        uint2 c0 = cvt4(b0), c1 = cvt4(b1);
        *reinterpret_cast<uint4*>(BsW[p]) = make_uint4(c0.x, c0.y, c1.x, c1.y);

        __syncthreads();   // LDS[p] visible; prev-iter loads already consumed

        // ---- prefetch tile k+1 (in flight across the whole compute phase)
        if (k0 + BK < K) {
            b0 = *reinterpret_cast<const float4*>(Fg + k0 + BK);
            b1 = *reinterpret_cast<const float4*>(Fg + k0 + BK + 4);
        }

        // ---- A fragments direct from global (L2-resident), fused cvt
        bf16x8 af[4];
        #pragma unroll
        for (int mi = 0; mi < 4; ++mi) {
            const float* ap = Ab + (size_t)mi * 16 * K + k0;
            float4 a0 = *reinterpret_cast<const float4*>(ap);
            float4 a1 = *reinterpret_cast<const float4*>(ap + 4);
            uint2 d0 = cvt4(a0), d1 = cvt4(a1);
            union { uint4 u; bf16x8 v; } t;
            t.u = make_uint4(d0.x, d0.y, d1.x, d1.y);
            af[mi] = t.v;
        }

        // ---- B fragments from LDS[p]
        const __hip_bfloat16* BsR = Bs[p];
        bf16x8 bfr[4];
        #pragma unroll
        for (int ni = 0; ni < 4; ++ni)
            bfr[ni] = *reinterpret_cast<const bf16x8*>(
                BsR + (ni * 16 + r15) * BK + quad * 8);

        #pragma unroll
        for (int mi = 0; mi < 4; ++mi)
            #pragma unroll
            for (int ni = 0; ni < 4; ++ni)
                acc[mi][ni] = __builtin_amdgcn_mfma_f32_16x16x32_bf16(
                    af[mi], bfr[ni], acc[mi][ni], 0, 0, 0);
        // NOTE: no second barrier — iter k+1 writes LDS[p^1] while laggards
        // read LDS[p]; buffer reuse is separated by the single barrier.
    }

    // ---- epilogue: C/D layout col = lane&15, row = quad*4 + e  [m89/m91]
    const int col0 = n0 + r15;
    #pragma unroll
    for (int mi = 0; mi < 4; ++mi) {
        const int row0 = w * 64 + mi * 16 + quad * 4;
        #pragma unroll
        for (int ni = 0; ni < 4; ++ni) {
            #pragma unroll
            for (int e = 0; e < 4; ++e) {
                C[(size_t)(row0 + e) * N + col0 + ni * 16] = acc[mi][ni][e];
            }
        }
    }
}

extern "C" void kernel_launch(void* const* d_in, const int* in_sizes, int n_in,
                              void* d_out, int out_size, void* d_ws, size_t ws_size,
                              hipStream_t stream) {
    const float* inputs   = (const float*)d_in[0];
    // d_in[1] = inputs_ema (unused), d_in[2] = indexes (unused)
    const float* features = (const float*)d_in[3];
    float* out = (float*)d_out;

    dim3 grid(N / BN);       // 1024 blocks
    dim3 block(THREADS);
    hipLaunchKernelGGL(dm_gemm, grid, block, 0, stream, inputs, features, out);
}